// Round 2
// baseline (494.848 us; speedup 1.0000x reference)
//
#include <hip/hip_runtime.h>

// LNCC, separable 5-tap Gaussian (sigma=1), fused single pass.
// (N=2, C=1, D=160, H=192, W=224) fp32 -> scalar.
// R2: register D-ring (unroll-by-5), float2/float4 packed LDS, 384-thread blocks.

#define NB 2
#define DD 160
#define HH 192
#define WW 224
#define SH 224
#define SD (224*192)
#define SN (224*192*160)

#define TW 32
#define TH 8
#define DCHUNK 40
#define NCHUNK (DD/DCHUNK)   // 4

__global__ __launch_bounds__(384, 6) void lncc_main(
    const float* __restrict__ A, const float* __restrict__ B,
    const float* __restrict__ M, double* __restrict__ acc)
{
    // LDS: raw interleaved (I,J) with +-2 W halo; packed W-blur moments.
    __shared__ float2 sIJ[12][36];      // 3456 B
    __shared__ float4 wbA[12][32];      // (bI, bII, bJ, bJJ)  6144 B
    __shared__ float  wbC[12][32];      // bIJ                 1536 B
    __shared__ float  redL[6], redM[6];

    const float KW[5] = {0.05448868f, 0.24420134f, 0.40261995f, 0.24420134f, 0.05448868f};

    const int wt = blockIdx.x;           // 0..6
    const int ht = blockIdx.y;           // 0..23
    const int zz = blockIdx.z;           // 0..7
    const int n  = zz >> 2;
    const int dc = zz & 3;
    const int w0 = wt * TW, h0 = ht * TH, d0 = dc * DCHUNK;

    const float* __restrict__ Ai = A + (size_t)n * SN;
    const float* __restrict__ Bi = B + (size_t)n * SN;
    const float* __restrict__ Mi = M + (size_t)n * SN;

    const int tid = threadIdx.x;
    const int r12 = tid >> 5;            // 0..11
    const int c   = tid & 31;            // 0..31

    // per-thread loop invariants
    const int gh  = h0 + r12 - 2;
    const bool hv = (unsigned)gh < (unsigned)HH;
    const int ghc = hv ? gh : 0;
    const size_t hwm = (size_t)ghc * SH + (w0 + c);          // main px
    const int gwl = w0 + c - 2;                              // c<2 halo
    const int gwr = w0 + c + 2;                              // c>=30 halo
    const bool lvalid = hv && (c < 2)  && (gwl >= 0);
    const bool rvalid = hv && (c >= 30) && (gwr < WW);
    const size_t hwl = (size_t)ghc * SH + (lvalid ? gwl : 0);
    const size_t hwr = (size_t)ghc * SH + (rvalid ? gwr : 0);
    const size_t mbase = (size_t)(h0 + r12) * SH + (w0 + c); // mask (r12<8 only)

    // register D-ring: 5 slots x 5 channels
    float rI[5], rJ[5], rIJ[5], rII[5], rJJ[5];
    float accL = 0.f, accM = 0.f;

    for (int ii = 0; ii < 9; ++ii) {
#pragma unroll
        for (int u = 0; u < 5; ++u) {
            const int i = ii * 5 + u;          // 0..44 (44 skipped)
            if (i < 44) {                      // block-uniform
                const int dd = d0 - 2 + i;
                const bool dv = (dd >= 0) && (dd < DD);
                const size_t dof = (size_t)(dv ? dd : 0) * SD;

                // ---- S1: load raw slice, interleave (I,J), zero-pad ----
                float vi = 0.f, vj = 0.f;
                if (dv && hv) { vi = Ai[dof + hwm]; vj = Bi[dof + hwm]; }
                sIJ[r12][c + 2] = make_float2(vi, vj);
                if (c < 2) {
                    float li = 0.f, lj = 0.f;
                    if (dv && lvalid) { li = Ai[dof + hwl]; lj = Bi[dof + hwl]; }
                    sIJ[r12][c] = make_float2(li, lj);
                } else if (c >= 30) {
                    float ri = 0.f, rj = 0.f;
                    if (dv && rvalid) { ri = Ai[dof + hwr]; rj = Bi[dof + hwr]; }
                    sIJ[r12][c + 4] = make_float2(ri, rj);
                }
                __syncthreads();

                // ---- S2: W-blur -> packed moments ----
                {
                    float bi = 0.f, bj = 0.f, bij = 0.f, bii = 0.f, bjj = 0.f;
#pragma unroll
                    for (int t = 0; t < 5; ++t) {
                        const float2 v = sIJ[r12][c + t];
                        const float k = KW[t];
                        bi  += k * v.x;
                        bj  += k * v.y;
                        bij += k * v.x * v.y;
                        bii += k * v.x * v.x;
                        bjj += k * v.y * v.y;
                    }
                    wbA[r12][c] = make_float4(bi, bii, bj, bjj);
                    wbC[r12][c] = bij;
                }
                __syncthreads();

                // ---- S3: H-blur into register ring slot u (rows 0..7) ----
                if (r12 < 8) {
                    float hI = 0.f, hII = 0.f, hJ = 0.f, hJJ = 0.f, hIJ = 0.f;
#pragma unroll
                    for (int t = 0; t < 5; ++t) {
                        const float k = KW[t];
                        const float4 a = wbA[r12 + t][c];
                        hI  += k * a.x;
                        hII += k * a.y;
                        hJ  += k * a.z;
                        hJJ += k * a.w;
                        hIJ += k * wbC[r12 + t][c];
                    }
                    rI[u] = hI; rII[u] = hII; rJ[u] = hJ; rJJ[u] = hJJ; rIJ[u] = hIJ;

                    // ---- S4: D-blur + LNCC for d = dd-2 (static ring slots) ----
                    if (i >= 4) {
                        float bI = 0.f, bJ = 0.f, bIJ = 0.f, bII = 0.f, bJJ = 0.f;
#pragma unroll
                        for (int t = 0; t < 5; ++t) {
                            const int sl = (u + 1 + t) % 5;   // compile-time
                            const float k = KW[t];
                            bI  += k * rI[sl];
                            bJ  += k * rJ[sl];
                            bIJ += k * rIJ[sl];
                            bII += k * rII[sl];
                            bJJ += k * rJJ[sl];
                        }
                        const float cross = bIJ - bI * bJ;
                        const float vI = fmaxf(bII - bI * bI, 0.f) + 1e-5f;
                        const float vJ = fmaxf(bJJ - bJ * bJ, 0.f) + 1e-5f;
                        const float lncc = 1.0f - cross * rsqrtf(vI * vJ);
                        const int d = dd - 2;
                        const float m = Mi[(size_t)d * SD + mbase];
                        accL += lncc * m;
                        accM += m;
                    }
                }
            }
        }
    }

    // ---- reduction: wave shuffle then cross-wave LDS ----
#pragma unroll
    for (int off = 32; off > 0; off >>= 1) {
        accL += __shfl_down(accL, off, 64);
        accM += __shfl_down(accM, off, 64);
    }
    const int wave = tid >> 6;
    if ((tid & 63) == 0) { redL[wave] = accL; redM[wave] = accM; }
    __syncthreads();
    if (tid == 0) {
        float sL = 0.f, sM = 0.f;
#pragma unroll
        for (int k = 0; k < 6; ++k) { sL += redL[k]; sM += redM[k]; }
        atomicAdd(&acc[0], (double)sL);
        atomicAdd(&acc[1], (double)sM);
    }
}

__global__ void lncc_final(const double* __restrict__ acc, float* __restrict__ out)
{
    out[0] = (float)(acc[0] / (acc[1] + 1e-8));
}

extern "C" void kernel_launch(void* const* d_in, const int* in_sizes, int n_in,
                              void* d_out, int out_size, void* d_ws, size_t ws_size,
                              hipStream_t stream)
{
    const float* A = (const float*)d_in[0];
    const float* B = (const float*)d_in[1];
    const float* M = (const float*)d_in[2];
    double* acc = (double*)d_ws;

    hipMemsetAsync(d_ws, 0, 2 * sizeof(double), stream);

    dim3 grid(WW / TW, HH / TH, NB * NCHUNK);   // (7, 24, 8)
    dim3 block(384);
    hipLaunchKernelGGL(lncc_main, grid, block, 0, stream, A, B, M, acc);
    hipLaunchKernelGGL(lncc_final, dim3(1), dim3(1), 0, stream, acc, (float*)d_out);
}

// Round 3
// 330.956 us; speedup vs baseline: 1.4952x; 1.4952x over previous
//
#include <hip/hip_runtime.h>

// LNCC, separable 5-tap Gaussian (sigma=1), fused single pass.
// (N=2, C=1, D=160, H=192, W=224) fp32 -> scalar.
// R3: D-pipeline as named-scalar shift registers (no spill), packed LDS,
//     symmetric-kernel FMA reduction.

#define NB 2
#define DD 160
#define HH 192
#define WW 224
#define SH 224
#define SD (224*192)
#define SN (224*192*160)

#define TW 32
#define TH 8
#define DCHUNK 40
#define NCHUNK (DD/DCHUNK)   // 4

#define K0 0.05448868f
#define K1 0.24420134f
#define K2 0.40261995f

__global__ __launch_bounds__(384) void lncc_main(
    const float* __restrict__ A, const float* __restrict__ B,
    const float* __restrict__ M, double* __restrict__ acc)
{
    __shared__ float2 sIJ[12][36];      // raw (I,J), W halo
    __shared__ float4 wbA[12][32];      // (bI, bII, bJ, bJJ)
    __shared__ float  wbC[12][32];      // bIJ
    __shared__ float  redL[6], redM[6];

    const int wt = blockIdx.x;           // 0..6
    const int ht = blockIdx.y;           // 0..23
    const int zz = blockIdx.z;           // 0..7
    const int n  = zz >> 2;
    const int dc = zz & 3;
    const int w0 = wt * TW, h0 = ht * TH, d0 = dc * DCHUNK;

    const float* __restrict__ Ai = A + (size_t)n * SN;
    const float* __restrict__ Bi = B + (size_t)n * SN;
    const float* __restrict__ Mi = M + (size_t)n * SN;

    const int tid = threadIdx.x;
    const int r12 = tid >> 5;            // 0..11
    const int c   = tid & 31;            // 0..31

    const int gh  = h0 + r12 - 2;
    const bool hv = (unsigned)gh < (unsigned)HH;
    const int ghc = hv ? gh : 0;
    const size_t hwm = (size_t)ghc * SH + (w0 + c);
    const int gwl = w0 + c - 2;
    const int gwr = w0 + c + 2;
    const bool lvalid = hv && (c < 2)  && (gwl >= 0);
    const bool rvalid = hv && (c >= 30) && (gwr < WW);
    const size_t hwl = (size_t)ghc * SH + (lvalid ? gwl : 0);
    const size_t hwr = (size_t)ghc * SH + (rvalid ? gwr : 0);
    const size_t mbase = (size_t)(h0 + r12) * SH + (w0 + c);

    // D-direction shift-register pipeline: p*0 = oldest (d-4) ... p*3 = d-1
    float pI0=0.f,pI1=0.f,pI2=0.f,pI3=0.f;
    float pJ0=0.f,pJ1=0.f,pJ2=0.f,pJ3=0.f;
    float pC0=0.f,pC1=0.f,pC2=0.f,pC3=0.f;   // IJ
    float pS0=0.f,pS1=0.f,pS2=0.f,pS3=0.f;   // II
    float pT0=0.f,pT1=0.f,pT2=0.f,pT3=0.f;   // JJ
    float accL = 0.f, accM = 0.f;

    for (int dd = d0 - 2; dd <= d0 + DCHUNK + 1; ++dd) {
        const bool dv = (dd >= 0) && (dd < DD);
        const size_t dof = (size_t)(dv ? dd : 0) * SD;

        // ---- S1: stage raw slice, interleaved (I,J), zero-padded ----
        float vi = 0.f, vj = 0.f;
        if (dv && hv) { vi = Ai[dof + hwm]; vj = Bi[dof + hwm]; }
        sIJ[r12][c + 2] = make_float2(vi, vj);
        if (c < 2) {
            float li = 0.f, lj = 0.f;
            if (dv && lvalid) { li = Ai[dof + hwl]; lj = Bi[dof + hwl]; }
            sIJ[r12][c] = make_float2(li, lj);
        } else if (c >= 30) {
            float ri = 0.f, rj = 0.f;
            if (dv && rvalid) { ri = Ai[dof + hwr]; rj = Bi[dof + hwr]; }
            sIJ[r12][c + 4] = make_float2(ri, rj);
        }
        __syncthreads();

        // ---- S2: W-blur (symmetric taps) -> packed moments ----
        {
            const float2 v0 = sIJ[r12][c];
            const float2 v1 = sIJ[r12][c + 1];
            const float2 v2 = sIJ[r12][c + 2];
            const float2 v3 = sIJ[r12][c + 3];
            const float2 v4 = sIJ[r12][c + 4];
            const float bi  = K0*(v0.x+v4.x) + K1*(v1.x+v3.x) + K2*v2.x;
            const float bj  = K0*(v0.y+v4.y) + K1*(v1.y+v3.y) + K2*v2.y;
            const float bij = K0*(v0.x*v0.y+v4.x*v4.y) + K1*(v1.x*v1.y+v3.x*v3.y) + K2*v2.x*v2.y;
            const float bii = K0*(v0.x*v0.x+v4.x*v4.x) + K1*(v1.x*v1.x+v3.x*v3.x) + K2*v2.x*v2.x;
            const float bjj = K0*(v0.y*v0.y+v4.y*v4.y) + K1*(v1.y*v1.y+v3.y*v3.y) + K2*v2.y*v2.y;
            wbA[r12][c] = make_float4(bi, bii, bj, bjj);
            wbC[r12][c] = bij;
        }
        __syncthreads();

        // ---- S3: H-blur (symmetric) -> newest pipeline stage ----
        if (r12 < 8) {
            const float4 a0 = wbA[r12][c];
            const float4 a1 = wbA[r12 + 1][c];
            const float4 a2 = wbA[r12 + 2][c];
            const float4 a3 = wbA[r12 + 3][c];
            const float4 a4 = wbA[r12 + 4][c];
            const float c0 = wbC[r12][c];
            const float c1 = wbC[r12 + 1][c];
            const float c2 = wbC[r12 + 2][c];
            const float c3 = wbC[r12 + 3][c];
            const float c4 = wbC[r12 + 4][c];
            const float hI  = K0*(a0.x+a4.x) + K1*(a1.x+a3.x) + K2*a2.x;
            const float hII = K0*(a0.y+a4.y) + K1*(a1.y+a3.y) + K2*a2.y;
            const float hJ  = K0*(a0.z+a4.z) + K1*(a1.z+a3.z) + K2*a2.z;
            const float hJJ = K0*(a0.w+a4.w) + K1*(a1.w+a3.w) + K2*a2.w;
            const float hIJ = K0*(c0+c4)     + K1*(c1+c3)     + K2*c2;

            // ---- S4: D-blur + LNCC for d = dd-2 ----
            if (dd >= d0 + 2) {
                const float bI  = K0*(pI0+hI)  + K1*(pI1+pI3) + K2*pI2;
                const float bJ  = K0*(pJ0+hJ)  + K1*(pJ1+pJ3) + K2*pJ2;
                const float bIJ = K0*(pC0+hIJ) + K1*(pC1+pC3) + K2*pC2;
                const float bII = K0*(pS0+hII) + K1*(pS1+pS3) + K2*pS2;
                const float bJJ = K0*(pT0+hJJ) + K1*(pT1+pT3) + K2*pT2;
                const float cross = bIJ - bI * bJ;
                const float vI = fmaxf(bII - bI * bI, 0.f) + 1e-5f;
                const float vJ = fmaxf(bJJ - bJ * bJ, 0.f) + 1e-5f;
                const float lncc = 1.0f - cross * rsqrtf(vI * vJ);
                const int d = dd - 2;
                const float m = Mi[(size_t)d * SD + mbase];
                accL += lncc * m;
                accM += m;
            }

            // rotate pipeline (pure register moves)
            pI0=pI1; pI1=pI2; pI2=pI3; pI3=hI;
            pJ0=pJ1; pJ1=pJ2; pJ2=pJ3; pJ3=hJ;
            pC0=pC1; pC1=pC2; pC2=pC3; pC3=hIJ;
            pS0=pS1; pS1=pS2; pS2=pS3; pS3=hII;
            pT0=pT1; pT1=pT2; pT2=pT3; pT3=hJJ;
        }
    }

    // ---- reduction ----
#pragma unroll
    for (int off = 32; off > 0; off >>= 1) {
        accL += __shfl_down(accL, off, 64);
        accM += __shfl_down(accM, off, 64);
    }
    const int wave = tid >> 6;
    if ((tid & 63) == 0) { redL[wave] = accL; redM[wave] = accM; }
    __syncthreads();
    if (tid == 0) {
        float sL = 0.f, sM = 0.f;
#pragma unroll
        for (int k = 0; k < 6; ++k) { sL += redL[k]; sM += redM[k]; }
        atomicAdd(&acc[0], (double)sL);
        atomicAdd(&acc[1], (double)sM);
    }
}

__global__ void lncc_final(const double* __restrict__ acc, float* __restrict__ out)
{
    out[0] = (float)(acc[0] / (acc[1] + 1e-8));
}

extern "C" void kernel_launch(void* const* d_in, const int* in_sizes, int n_in,
                              void* d_out, int out_size, void* d_ws, size_t ws_size,
                              hipStream_t stream)
{
    const float* A = (const float*)d_in[0];
    const float* B = (const float*)d_in[1];
    const float* M = (const float*)d_in[2];
    double* acc = (double*)d_ws;

    hipMemsetAsync(d_ws, 0, 2 * sizeof(double), stream);

    dim3 grid(WW / TW, HH / TH, NB * NCHUNK);   // (7, 24, 8)
    dim3 block(384);
    hipLaunchKernelGGL(lncc_main, grid, block, 0, stream, A, B, M, acc);
    hipLaunchKernelGGL(lncc_final, dim3(1), dim3(1), 0, stream, acc, (float*)d_out);
}

// Round 4
// 236.730 us; speedup vs baseline: 2.0904x; 1.3980x over previous
//
#include <hip/hip_runtime.h>

// LNCC, separable 5-tap Gaussian (sigma=1), fused single pass.
// (N=2, C=1, D=160, H=192, W=224) fp32 -> scalar.
// R4: software-pipelined slice loop (stage | W-blur | H-blur+D shifted by 1),
//     double-buffered LDS, ONE barrier per slice, register prefetch of
//     next slice + mask, DCHUNK=80.

#define NB 2
#define DD 160
#define HH 192
#define WW 224
#define SH 224
#define SD (224*192)
#define SN (224*192*160)

#define TW 32
#define TH 8
#define DCHUNK 80
#define NCHUNK (DD/DCHUNK)   // 2

#define K0 0.05448868f
#define K1 0.24420134f
#define K2 0.40261995f

__global__ __launch_bounds__(384) void lncc_main(
    const float* __restrict__ A, const float* __restrict__ B,
    const float* __restrict__ M, double* __restrict__ acc)
{
    __shared__ float2 sIJ[2][12][36];   // raw (I,J), double-buffered
    __shared__ float4 wbA[2][12][32];   // (bI,bII,bJ,bJJ), double-buffered
    __shared__ float  wbC[2][12][32];   // bIJ
    __shared__ float  redL[6], redM[6];

    const int wt = blockIdx.x;           // 0..6
    const int ht = blockIdx.y;           // 0..23
    const int zz = blockIdx.z;           // 0..3
    const int n  = zz >> 1;
    const int dc = zz & 1;
    const int w0 = wt * TW, h0 = ht * TH, d0 = dc * DCHUNK;

    const float* __restrict__ Ai = A + (size_t)n * SN;
    const float* __restrict__ Bi = B + (size_t)n * SN;
    const float* __restrict__ Mi = M + (size_t)n * SN;

    const int tid = threadIdx.x;
    const int r12 = tid >> 5;            // 0..11
    const int c   = tid & 31;            // 0..31

    const int gh  = h0 + r12 - 2;
    const bool hv = (unsigned)gh < (unsigned)HH;
    const int ghc = hv ? gh : 0;
    const size_t hwm = (size_t)ghc * SH + (w0 + c);
    const int gwl = w0 + c - 2, gwr = w0 + c + 2;
    const bool lv = hv && (c < 2)   && (gwl >= 0);
    const bool rv = hv && (c >= 30) && (gwr < WW);
    const bool anyh = lv || rv;
    const size_t hwh = (size_t)ghc * SH + (lv ? gwl : (rv ? gwr : 0));
    const size_t mbase = (size_t)(h0 + r12) * SH + (w0 + c);

    // D-direction shift-register pipeline (oldest..newest)
    float pI0=0.f,pI1=0.f,pI2=0.f,pI3=0.f;
    float pJ0=0.f,pJ1=0.f,pJ2=0.f,pJ3=0.f;
    float pC0=0.f,pC1=0.f,pC2=0.f,pC3=0.f;
    float pS0=0.f,pS1=0.f,pS2=0.f,pS3=0.f;
    float pT0=0.f,pT1=0.f,pT2=0.f,pT3=0.f;
    float accL = 0.f, accM = 0.f;

    // prefetch registers for the slice to be staged at iteration k
    float nI = 0.f, nJ = 0.f, nHI = 0.f, nHJ = 0.f;
    {
        const int dd = d0 - 2;
        const bool dv = (dd >= 0);
        const size_t dof = (size_t)(dv ? dd : 0) * SD;
        if (dv && hv)   { nI  = Ai[dof + hwm]; nJ  = Bi[dof + hwm]; }
        if (dv && anyh) { nHI = Ai[dof + hwh]; nHJ = Bi[dof + hwh]; }
    }

    const int NIT = DCHUNK + 6;          // 86
    for (int k = 0; k < NIT; ++k) {
        const int pw = k & 1;            // parity of slice staged THIS iter
        const int px = pw ^ 1;           // parity of slice staged LAST iter

        // ---- W: stage prefetched raw slice (slices d0-2 .. d0+DCHUNK+1) ----
        if (k < DCHUNK + 4) {
            sIJ[pw][r12][c + 2] = make_float2(nI, nJ);
            if (c < 2)        sIJ[pw][r12][c]     = make_float2(nHI, nHJ);
            else if (c >= 30) sIJ[pw][r12][c + 4] = make_float2(nHI, nHJ);
        }

        // ---- prefetch slice k+1 and this iteration's mask row ----
        nI = nJ = nHI = nHJ = 0.f;
        {
            const int dd = d0 - 1 + k;
            const bool dv = (k + 1 < DCHUNK + 4) && (dd >= 0) && (dd < DD);
            const size_t dof = (size_t)(dv ? dd : 0) * SD;
            if (dv && hv)   { nI  = Ai[dof + hwm]; nJ  = Bi[dof + hwm]; }
            if (dv && anyh) { nHI = Ai[dof + hwh]; nHJ = Bi[dof + hwh]; }
        }
        const int  dout = d0 - 6 + k;
        const bool doY  = (k >= 2);                   // k <= 85 always
        const bool outv = (k >= 6) && (r12 < 8);      // dout in [d0, d0+DCHUNK)
        float mval = 0.f;
        if (outv) mval = Mi[(size_t)dout * SD + mbase];

        // ---- X: W-blur of slice staged last iteration ----
        if (k >= 1 && k <= DCHUNK + 4) {
            const float2 v0 = sIJ[px][r12][c];
            const float2 v1 = sIJ[px][r12][c + 1];
            const float2 v2 = sIJ[px][r12][c + 2];
            const float2 v3 = sIJ[px][r12][c + 3];
            const float2 v4 = sIJ[px][r12][c + 4];
            const float bi  = K0*(v0.x+v4.x) + K1*(v1.x+v3.x) + K2*v2.x;
            const float bj  = K0*(v0.y+v4.y) + K1*(v1.y+v3.y) + K2*v2.y;
            const float bij = K0*(v0.x*v0.y+v4.x*v4.y) + K1*(v1.x*v1.y+v3.x*v3.y) + K2*v2.x*v2.y;
            const float bii = K0*(v0.x*v0.x+v4.x*v4.x) + K1*(v1.x*v1.x+v3.x*v3.x) + K2*v2.x*v2.x;
            const float bjj = K0*(v0.y*v0.y+v4.y*v4.y) + K1*(v1.y*v1.y+v3.y*v3.y) + K2*v2.y*v2.y;
            wbA[px][r12][c] = make_float4(bi, bii, bj, bjj);
            wbC[px][r12][c] = bij;
        }

        // ---- Y: H-blur of slice staged two iterations ago + D-pipeline ----
        if (doY && r12 < 8) {
            const float4 a0 = wbA[pw][r12][c];
            const float4 a1 = wbA[pw][r12 + 1][c];
            const float4 a2 = wbA[pw][r12 + 2][c];
            const float4 a3 = wbA[pw][r12 + 3][c];
            const float4 a4 = wbA[pw][r12 + 4][c];
            const float c0 = wbC[pw][r12][c];
            const float c1 = wbC[pw][r12 + 1][c];
            const float c2 = wbC[pw][r12 + 2][c];
            const float c3 = wbC[pw][r12 + 3][c];
            const float c4 = wbC[pw][r12 + 4][c];
            const float hI  = K0*(a0.x+a4.x) + K1*(a1.x+a3.x) + K2*a2.x;
            const float hII = K0*(a0.y+a4.y) + K1*(a1.y+a3.y) + K2*a2.y;
            const float hJ  = K0*(a0.z+a4.z) + K1*(a1.z+a3.z) + K2*a2.z;
            const float hJJ = K0*(a0.w+a4.w) + K1*(a1.w+a3.w) + K2*a2.w;
            const float hIJ = K0*(c0+c4)     + K1*(c1+c3)     + K2*c2;

            if (outv) {
                const float bI  = K0*(pI0+hI)  + K1*(pI1+pI3) + K2*pI2;
                const float bJ  = K0*(pJ0+hJ)  + K1*(pJ1+pJ3) + K2*pJ2;
                const float bIJ = K0*(pC0+hIJ) + K1*(pC1+pC3) + K2*pC2;
                const float bII = K0*(pS0+hII) + K1*(pS1+pS3) + K2*pS2;
                const float bJJ = K0*(pT0+hJJ) + K1*(pT1+pT3) + K2*pT2;
                const float cross = bIJ - bI * bJ;
                const float vI = fmaxf(bII - bI * bI, 0.f) + 1e-5f;
                const float vJ = fmaxf(bJJ - bJ * bJ, 0.f) + 1e-5f;
                const float lncc = 1.0f - cross * rsqrtf(vI * vJ);
                accL += lncc * mval;
                accM += mval;
            }

            pI0=pI1; pI1=pI2; pI2=pI3; pI3=hI;
            pJ0=pJ1; pJ1=pJ2; pJ2=pJ3; pJ3=hJ;
            pC0=pC1; pC1=pC2; pC2=pC3; pC3=hIJ;
            pS0=pS1; pS1=pS2; pS2=pS3; pS3=hII;
            pT0=pT1; pT1=pT2; pT2=pT3; pT3=hJJ;
        }

        __syncthreads();
    }

    // ---- reduction ----
#pragma unroll
    for (int off = 32; off > 0; off >>= 1) {
        accL += __shfl_down(accL, off, 64);
        accM += __shfl_down(accM, off, 64);
    }
    const int wave = tid >> 6;
    if ((tid & 63) == 0) { redL[wave] = accL; redM[wave] = accM; }
    __syncthreads();
    if (tid == 0) {
        float sL = 0.f, sM = 0.f;
#pragma unroll
        for (int kk = 0; kk < 6; ++kk) { sL += redL[kk]; sM += redM[kk]; }
        atomicAdd(&acc[0], (double)sL);
        atomicAdd(&acc[1], (double)sM);
    }
}

__global__ void lncc_final(const double* __restrict__ acc, float* __restrict__ out)
{
    out[0] = (float)(acc[0] / (acc[1] + 1e-8));
}

extern "C" void kernel_launch(void* const* d_in, const int* in_sizes, int n_in,
                              void* d_out, int out_size, void* d_ws, size_t ws_size,
                              hipStream_t stream)
{
    const float* A = (const float*)d_in[0];
    const float* B = (const float*)d_in[1];
    const float* M = (const float*)d_in[2];
    double* acc = (double*)d_ws;

    hipMemsetAsync(d_ws, 0, 2 * sizeof(double), stream);

    dim3 grid(WW / TW, HH / TH, NB * NCHUNK);   // (7, 24, 4)
    dim3 block(384);
    hipLaunchKernelGGL(lncc_main, grid, block, 0, stream, A, B, M, acc);
    hipLaunchKernelGGL(lncc_final, dim3(1), dim3(1), 0, stream, acc, (float*)d_out);
}

// Round 5
// 236.401 us; speedup vs baseline: 2.0933x; 1.0014x over previous
//
#include <hip/hip_runtime.h>

// LNCC, separable 5-tap Gaussian (sigma=1), fused single pass.
// (N=2, C=1, D=160, H=192, W=224) fp32 -> scalar.
// R5: R4 pipeline + 32-bit saddr-form addressing + slice loop unrolled x10
//     (kills ring-rotation movs and parity math), NIT padded to 90.

#define NB 2
#define DD 160
#define HH 192
#define WW 224
#define SH 224
#define SD (224*192)
#define SN (224*192*160)

#define TW 32
#define TH 8
#define DCHUNK 80
#define NCHUNK (DD/DCHUNK)   // 2

#define K0 0.05448868f
#define K1 0.24420134f
#define K2 0.40261995f

__global__ __launch_bounds__(384) void lncc_main(
    const float* __restrict__ A, const float* __restrict__ B,
    const float* __restrict__ M, double* __restrict__ acc)
{
    __shared__ float2 sIJ[2][12][36];
    __shared__ float4 wbA[2][12][32];
    __shared__ float  wbC[2][12][32];
    __shared__ float  redL[6], redM[6];

    const int wt = blockIdx.x;           // 0..6
    const int ht = blockIdx.y;           // 0..23
    const int zz = blockIdx.z;           // 0..3
    const int n  = zz >> 1;
    const int dc = zz & 1;
    const int w0 = wt * TW, h0 = ht * TH, d0 = dc * DCHUNK;

    const float* __restrict__ Ai = A + (size_t)n * SN;
    const float* __restrict__ Bi = B + (size_t)n * SN;
    const float* __restrict__ Mi = M + (size_t)n * SN;

    const int tid = threadIdx.x;
    const int r12 = tid >> 5;            // 0..11
    const int c   = tid & 31;            // 0..31

    const int gh  = h0 + r12 - 2;
    const bool hv = (unsigned)gh < (unsigned)HH;
    const int ghc = hv ? gh : 0;
    const int hwm = ghc * SH + (w0 + c);          // 32-bit offsets
    const int gwl = w0 + c - 2, gwr = w0 + c + 2;
    const bool lv = hv && (c < 2)   && (gwl >= 0);
    const bool rv = hv && (c >= 30) && (gwr < WW);
    const bool anyh = lv || rv;
    const int hwh = ghc * SH + (lv ? gwl : (rv ? gwr : 0));
    const int mbase = (h0 + r12) * SH + (w0 + c);

    // D-direction shift-register pipeline (oldest..newest)
    float pI0=0.f,pI1=0.f,pI2=0.f,pI3=0.f;
    float pJ0=0.f,pJ1=0.f,pJ2=0.f,pJ3=0.f;
    float pC0=0.f,pC1=0.f,pC2=0.f,pC3=0.f;
    float pS0=0.f,pS1=0.f,pS2=0.f,pS3=0.f;
    float pT0=0.f,pT1=0.f,pT2=0.f,pT3=0.f;
    float accL = 0.f, accM = 0.f;

    // prefetch registers for the slice staged at iteration k
    float nI = 0.f, nJ = 0.f, nHI = 0.f, nHJ = 0.f;
    {
        const int dd = d0 - 2;
        if (dd >= 0) {
            const int dof = dd * SD;
            if (hv)   { nI  = Ai[dof + hwm]; nJ  = Bi[dof + hwm]; }
            if (anyh) { nHI = Ai[dof + hwh]; nHJ = Bi[dof + hwh]; }
        }
    }

    for (int kb = 0; kb < 9; ++kb) {
#pragma unroll
        for (int u = 0; u < 10; ++u) {
            const int k = kb * 10 + u;
            const int pw = u & 1;        // compile-time parity
            const int px = pw ^ 1;

            // ---- W: stage prefetched raw slice ----
            if (k < DCHUNK + 4) {
                sIJ[pw][r12][c + 2] = make_float2(nI, nJ);
                if (c < 2)        sIJ[pw][r12][c]     = make_float2(nHI, nHJ);
                else if (c >= 30) sIJ[pw][r12][c + 4] = make_float2(nHI, nHJ);
            }

            // ---- prefetch slice k+1 ----
            nI = nJ = nHI = nHJ = 0.f;
            {
                const int dd = d0 - 1 + k;
                if ((k + 1 < DCHUNK + 4) && (dd >= 0) && (dd < DD)) {
                    const int dof = dd * SD;
                    if (hv)   { nI  = Ai[dof + hwm]; nJ  = Bi[dof + hwm]; }
                    if (anyh) { nHI = Ai[dof + hwh]; nHJ = Bi[dof + hwh]; }
                }
            }
            // ---- this iteration's mask value ----
            const int  dout = d0 - 6 + k;
            const bool outv = (k >= 6) && (k < DCHUNK + 6) && (r12 < 8);
            float mval = 0.f;
            if (outv) mval = Mi[dout * SD + mbase];

            // ---- X: W-blur of slice staged last iteration ----
            if (k >= 1 && k <= DCHUNK + 4) {
                const float2 v0 = sIJ[px][r12][c];
                const float2 v1 = sIJ[px][r12][c + 1];
                const float2 v2 = sIJ[px][r12][c + 2];
                const float2 v3 = sIJ[px][r12][c + 3];
                const float2 v4 = sIJ[px][r12][c + 4];
                const float bi  = K0*(v0.x+v4.x) + K1*(v1.x+v3.x) + K2*v2.x;
                const float bj  = K0*(v0.y+v4.y) + K1*(v1.y+v3.y) + K2*v2.y;
                const float bij = K0*(v0.x*v0.y+v4.x*v4.y) + K1*(v1.x*v1.y+v3.x*v3.y) + K2*v2.x*v2.y;
                const float bii = K0*(v0.x*v0.x+v4.x*v4.x) + K1*(v1.x*v1.x+v3.x*v3.x) + K2*v2.x*v2.x;
                const float bjj = K0*(v0.y*v0.y+v4.y*v4.y) + K1*(v1.y*v1.y+v3.y*v3.y) + K2*v2.y*v2.y;
                wbA[px][r12][c] = make_float4(bi, bii, bj, bjj);
                wbC[px][r12][c] = bij;
            }

            // ---- Y: H-blur of slice staged two iters ago + D-pipeline ----
            if (k >= 2 && r12 < 8) {
                const float4 a0 = wbA[pw][r12][c];
                const float4 a1 = wbA[pw][r12 + 1][c];
                const float4 a2 = wbA[pw][r12 + 2][c];
                const float4 a3 = wbA[pw][r12 + 3][c];
                const float4 a4 = wbA[pw][r12 + 4][c];
                const float c0 = wbC[pw][r12][c];
                const float c1 = wbC[pw][r12 + 1][c];
                const float c2 = wbC[pw][r12 + 2][c];
                const float c3 = wbC[pw][r12 + 3][c];
                const float c4 = wbC[pw][r12 + 4][c];
                const float hI  = K0*(a0.x+a4.x) + K1*(a1.x+a3.x) + K2*a2.x;
                const float hII = K0*(a0.y+a4.y) + K1*(a1.y+a3.y) + K2*a2.y;
                const float hJ  = K0*(a0.z+a4.z) + K1*(a1.z+a3.z) + K2*a2.z;
                const float hJJ = K0*(a0.w+a4.w) + K1*(a1.w+a3.w) + K2*a2.w;
                const float hIJ = K0*(c0+c4)     + K1*(c1+c3)     + K2*c2;

                if (outv) {
                    const float bI  = K0*(pI0+hI)  + K1*(pI1+pI3) + K2*pI2;
                    const float bJ  = K0*(pJ0+hJ)  + K1*(pJ1+pJ3) + K2*pJ2;
                    const float bIJ = K0*(pC0+hIJ) + K1*(pC1+pC3) + K2*pC2;
                    const float bII = K0*(pS0+hII) + K1*(pS1+pS3) + K2*pS2;
                    const float bJJ = K0*(pT0+hJJ) + K1*(pT1+pT3) + K2*pT2;
                    const float cross = bIJ - bI * bJ;
                    const float vI = fmaxf(bII - bI * bI, 0.f) + 1e-5f;
                    const float vJ = fmaxf(bJJ - bJ * bJ, 0.f) + 1e-5f;
                    const float lncc = 1.0f - cross * rsqrtf(vI * vJ);
                    accL += lncc * mval;
                    accM += mval;
                }

                pI0=pI1; pI1=pI2; pI2=pI3; pI3=hI;
                pJ0=pJ1; pJ1=pJ2; pJ2=pJ3; pJ3=hJ;
                pC0=pC1; pC1=pC2; pC2=pC3; pC3=hIJ;
                pS0=pS1; pS1=pS2; pS2=pS3; pS3=hII;
                pT0=pT1; pT1=pT2; pT2=pT3; pT3=hJJ;
            }

            __syncthreads();
        }
    }

    // ---- reduction ----
#pragma unroll
    for (int off = 32; off > 0; off >>= 1) {
        accL += __shfl_down(accL, off, 64);
        accM += __shfl_down(accM, off, 64);
    }
    const int wave = tid >> 6;
    if ((tid & 63) == 0) { redL[wave] = accL; redM[wave] = accM; }
    __syncthreads();
    if (tid == 0) {
        float sL = 0.f, sM = 0.f;
#pragma unroll
        for (int kk = 0; kk < 6; ++kk) { sL += redL[kk]; sM += redM[kk]; }
        atomicAdd(&acc[0], (double)sL);
        atomicAdd(&acc[1], (double)sM);
    }
}

__global__ void lncc_final(const double* __restrict__ acc, float* __restrict__ out)
{
    out[0] = (float)(acc[0] / (acc[1] + 1e-8));
}

extern "C" void kernel_launch(void* const* d_in, const int* in_sizes, int n_in,
                              void* d_out, int out_size, void* d_ws, size_t ws_size,
                              hipStream_t stream)
{
    const float* A = (const float*)d_in[0];
    const float* B = (const float*)d_in[1];
    const float* M = (const float*)d_in[2];
    double* acc = (double*)d_ws;

    hipMemsetAsync(d_ws, 0, 2 * sizeof(double), stream);

    dim3 grid(WW / TW, HH / TH, NB * NCHUNK);   // (7, 24, 4)
    dim3 block(384);
    hipLaunchKernelGGL(lncc_main, grid, block, 0, stream, A, B, M, acc);
    hipLaunchKernelGGL(lncc_final, dim3(1), dim3(1), 0, stream, acc, (float*)d_out);
}

// Round 6
// 235.258 us; speedup vs baseline: 2.1034x; 1.0049x over previous
//
#include <hip/hip_runtime.h>

// LNCC, separable 5-tap Gaussian (sigma=1), fused single pass.
// (N=2, C=1, D=160, H=192, W=224) fp32 -> scalar.
// R6: tile reshaped for occupancy: TH=16 (640 thr, halo-row overhead 1.25x),
//     DCHUNK=20 -> grid 1344 blocks (5.25/CU, 3 resident = 30 waves/CU).
//     Keeps R4's software pipeline: one barrier per slice, register prefetch.

#define NB 2
#define DD 160
#define HH 192
#define WW 224
#define SH 224
#define SD (224*192)
#define SN (224*192*160)

#define TW 32
#define TH 16
#define ROWS (TH+4)          // 20
#define DCHUNK 20
#define NCHUNK (DD/DCHUNK)   // 8

#define K0 0.05448868f
#define K1 0.24420134f
#define K2 0.40261995f

__global__ __launch_bounds__(640) void lncc_main(
    const float* __restrict__ A, const float* __restrict__ B,
    const float* __restrict__ M, double* __restrict__ acc)
{
    __shared__ float2 sIJ[2][ROWS][36];   // raw (I,J) + W halo, dbuf
    __shared__ float4 wbA[2][ROWS][32];   // (bI,bII,bJ,bJJ), dbuf
    __shared__ float  wbC[2][ROWS][32];   // bIJ, dbuf
    __shared__ float  redL[10], redM[10];

    const int wt = blockIdx.x;           // 0..6
    const int ht = blockIdx.y;           // 0..11
    const int zz = blockIdx.z;           // 0..15
    const int n  = zz >> 3;
    const int dc = zz & 7;
    const int w0 = wt * TW, h0 = ht * TH, d0 = dc * DCHUNK;

    const float* __restrict__ Ai = A + (size_t)n * SN;
    const float* __restrict__ Bi = B + (size_t)n * SN;
    const float* __restrict__ Mi = M + (size_t)n * SN;

    const int tid = threadIdx.x;
    const int r   = tid >> 5;            // 0..19
    const int c   = tid & 31;            // 0..31

    const int gh  = h0 + r - 2;
    const bool hv = (unsigned)gh < (unsigned)HH;
    const int ghc = hv ? gh : 0;
    const int hwm = ghc * SH + (w0 + c);          // 32-bit offsets
    const int gwl = w0 + c - 2, gwr = w0 + c + 2;
    const bool lv = hv && (c < 2)   && (gwl >= 0);
    const bool rv = hv && (c >= 30) && (gwr < WW);
    const bool anyh = lv || rv;
    const int hwh = ghc * SH + (lv ? gwl : (rv ? gwr : 0));
    const int mbase = (h0 + r) * SH + (w0 + c);

    // D-direction shift-register pipeline (oldest..newest)
    float pI0=0.f,pI1=0.f,pI2=0.f,pI3=0.f;
    float pJ0=0.f,pJ1=0.f,pJ2=0.f,pJ3=0.f;
    float pC0=0.f,pC1=0.f,pC2=0.f,pC3=0.f;
    float pS0=0.f,pS1=0.f,pS2=0.f,pS3=0.f;
    float pT0=0.f,pT1=0.f,pT2=0.f,pT3=0.f;
    float accL = 0.f, accM = 0.f;

    // prefetch registers for the slice staged at iteration k
    float nI = 0.f, nJ = 0.f, nHI = 0.f, nHJ = 0.f;
    {
        const int dd = d0 - 2;
        if (dd >= 0) {
            const int dof = dd * SD;
            if (hv)   { nI  = Ai[dof + hwm]; nJ  = Bi[dof + hwm]; }
            if (anyh) { nHI = Ai[dof + hwh]; nHJ = Bi[dof + hwh]; }
        }
    }

    const int NIT = DCHUNK + 6;          // 26
    for (int k = 0; k < NIT; ++k) {
        const int pw = k & 1;            // parity staged THIS iter
        const int px = pw ^ 1;

        // ---- W: stage prefetched raw slice (slices d0-2 .. d0+DCHUNK+1) ----
        if (k < DCHUNK + 4) {
            sIJ[pw][r][c + 2] = make_float2(nI, nJ);
            if (c < 2)        sIJ[pw][r][c]     = make_float2(nHI, nHJ);
            else if (c >= 30) sIJ[pw][r][c + 4] = make_float2(nHI, nHJ);
        }

        // ---- prefetch slice k+1 ----
        nI = nJ = nHI = nHJ = 0.f;
        {
            const int dd = d0 - 1 + k;
            if ((k + 1 < DCHUNK + 4) && (dd >= 0) && (dd < DD)) {
                const int dof = dd * SD;
                if (hv)   { nI  = Ai[dof + hwm]; nJ  = Bi[dof + hwm]; }
                if (anyh) { nHI = Ai[dof + hwh]; nHJ = Bi[dof + hwh]; }
            }
        }
        // ---- this iteration's mask value ----
        const int  dout = d0 - 6 + k;
        const bool outv = (k >= 6) && (r < TH);
        float mval = 0.f;
        if (outv) mval = Mi[dout * SD + mbase];

        // ---- X: W-blur of slice staged last iteration ----
        if (k >= 1 && k <= DCHUNK + 4) {
            const float2 v0 = sIJ[px][r][c];
            const float2 v1 = sIJ[px][r][c + 1];
            const float2 v2 = sIJ[px][r][c + 2];
            const float2 v3 = sIJ[px][r][c + 3];
            const float2 v4 = sIJ[px][r][c + 4];
            const float bi  = K0*(v0.x+v4.x) + K1*(v1.x+v3.x) + K2*v2.x;
            const float bj  = K0*(v0.y+v4.y) + K1*(v1.y+v3.y) + K2*v2.y;
            const float bij = K0*(v0.x*v0.y+v4.x*v4.y) + K1*(v1.x*v1.y+v3.x*v3.y) + K2*v2.x*v2.y;
            const float bii = K0*(v0.x*v0.x+v4.x*v4.x) + K1*(v1.x*v1.x+v3.x*v3.x) + K2*v2.x*v2.x;
            const float bjj = K0*(v0.y*v0.y+v4.y*v4.y) + K1*(v1.y*v1.y+v3.y*v3.y) + K2*v2.y*v2.y;
            wbA[px][r][c] = make_float4(bi, bii, bj, bjj);
            wbC[px][r][c] = bij;
        }

        // ---- Y: H-blur of slice staged two iters ago + D-pipeline ----
        if (k >= 2 && r < TH) {
            const float4 a0 = wbA[pw][r][c];
            const float4 a1 = wbA[pw][r + 1][c];
            const float4 a2 = wbA[pw][r + 2][c];
            const float4 a3 = wbA[pw][r + 3][c];
            const float4 a4 = wbA[pw][r + 4][c];
            const float c0 = wbC[pw][r][c];
            const float c1 = wbC[pw][r + 1][c];
            const float c2 = wbC[pw][r + 2][c];
            const float c3 = wbC[pw][r + 3][c];
            const float c4 = wbC[pw][r + 4][c];
            const float hI  = K0*(a0.x+a4.x) + K1*(a1.x+a3.x) + K2*a2.x;
            const float hII = K0*(a0.y+a4.y) + K1*(a1.y+a3.y) + K2*a2.y;
            const float hJ  = K0*(a0.z+a4.z) + K1*(a1.z+a3.z) + K2*a2.z;
            const float hJJ = K0*(a0.w+a4.w) + K1*(a1.w+a3.w) + K2*a2.w;
            const float hIJ = K0*(c0+c4)     + K1*(c1+c3)     + K2*c2;

            if (outv) {
                const float bI  = K0*(pI0+hI)  + K1*(pI1+pI3) + K2*pI2;
                const float bJ  = K0*(pJ0+hJ)  + K1*(pJ1+pJ3) + K2*pJ2;
                const float bIJ = K0*(pC0+hIJ) + K1*(pC1+pC3) + K2*pC2;
                const float bII = K0*(pS0+hII) + K1*(pS1+pS3) + K2*pS2;
                const float bJJ = K0*(pT0+hJJ) + K1*(pT1+pT3) + K2*pT2;
                const float cross = bIJ - bI * bJ;
                const float vI = fmaxf(bII - bI * bI, 0.f) + 1e-5f;
                const float vJ = fmaxf(bJJ - bJ * bJ, 0.f) + 1e-5f;
                const float lncc = 1.0f - cross * rsqrtf(vI * vJ);
                accL += lncc * mval;
                accM += mval;
            }

            pI0=pI1; pI1=pI2; pI2=pI3; pI3=hI;
            pJ0=pJ1; pJ1=pJ2; pJ2=pJ3; pJ3=hJ;
            pC0=pC1; pC1=pC2; pC2=pC3; pC3=hIJ;
            pS0=pS1; pS1=pS2; pS2=pS3; pS3=hII;
            pT0=pT1; pT1=pT2; pT2=pT3; pT3=hJJ;
        }

        __syncthreads();
    }

    // ---- reduction ----
#pragma unroll
    for (int off = 32; off > 0; off >>= 1) {
        accL += __shfl_down(accL, off, 64);
        accM += __shfl_down(accM, off, 64);
    }
    const int wave = tid >> 6;
    if ((tid & 63) == 0) { redL[wave] = accL; redM[wave] = accM; }
    __syncthreads();
    if (tid == 0) {
        float sL = 0.f, sM = 0.f;
#pragma unroll
        for (int kk = 0; kk < 10; ++kk) { sL += redL[kk]; sM += redM[kk]; }
        atomicAdd(&acc[0], (double)sL);
        atomicAdd(&acc[1], (double)sM);
    }
}

__global__ void lncc_final(const double* __restrict__ acc, float* __restrict__ out)
{
    out[0] = (float)(acc[0] / (acc[1] + 1e-8));
}

extern "C" void kernel_launch(void* const* d_in, const int* in_sizes, int n_in,
                              void* d_out, int out_size, void* d_ws, size_t ws_size,
                              hipStream_t stream)
{
    const float* A = (const float*)d_in[0];
    const float* B = (const float*)d_in[1];
    const float* M = (const float*)d_in[2];
    double* acc = (double*)d_ws;

    hipMemsetAsync(d_ws, 0, 2 * sizeof(double), stream);

    dim3 grid(WW / TW, HH / TH, NB * NCHUNK);   // (7, 12, 16) = 1344 blocks
    dim3 block(640);
    hipLaunchKernelGGL(lncc_main, grid, block, 0, stream, A, B, M, acc);
    hipLaunchKernelGGL(lncc_final, dim3(1), dim3(1), 0, stream, acc, (float*)d_out);
}